// Round 1
// baseline (2474.191 us; speedup 1.0000x reference)
//
#include <hip/hip_runtime.h>

#define N_DRUG 20000
#define N_DIS  10000
#define N_ATTR 2000
#define T_ATTR 8
#define E_MT   500000
#define E_HA   100000
#define E_LBL  200000
#define HC     128

__device__ __forceinline__ float leakyf(float x) { return x >= 0.f ? x : 0.01f * x; }

// ---------------- CSR build ----------------
__global__ void k_count(const int* __restrict__ idx, int n, int idxStrideZ,
                        int* __restrict__ cnt, int cntStrideZ) {
  int z = blockIdx.z;
  const int* p = idx + (size_t)z * idxStrideZ;
  int* c = cnt + (size_t)z * cntStrideZ;
  for (int i = blockIdx.x * blockDim.x + threadIdx.x; i < n; i += gridDim.x * blockDim.x)
    atomicAdd(&c[p[i]], 1);
}

// cnt layout: [0,10000) mt_dst | [10000,30000) mt_src | [30000,46000) ha_dst 8x2000 | [46000,206000) ha_src 8x20000
// off layout: 0 (10001) | 10001 (20001) | 30002 + t*2001 | 46010 + t*20001   (total 206018)
__global__ void k_scan(const int* __restrict__ cnt, int* __restrict__ off, int* __restrict__ cur) {
  int id = blockIdx.x;
  int cbase, obase, n;
  if (id == 0)      { cbase = 0;      obase = 0;      n = N_DIS; }
  else if (id == 1) { cbase = 10000;  obase = 10001;  n = N_DRUG; }
  else if (id < 10) { int t = id - 2;  cbase = 30000 + t * 2000;  obase = 30002 + t * 2001;  n = N_ATTR; }
  else              { int t = id - 10; cbase = 46000 + t * 20000; obase = 46010 + t * 20001; n = N_DRUG; }
  __shared__ int ssum[256];
  int t = threadIdx.x;
  int per = (n + 255) >> 8;
  int lo = t * per; if (lo > n) lo = n;
  int hi = lo + per; if (hi > n) hi = n;
  int s = 0;
  for (int i = lo; i < hi; i++) s += cnt[cbase + i];
  ssum[t] = s;
  __syncthreads();
  if (t == 0) {
    int run = 0;
    for (int i = 0; i < 256; i++) { int v = ssum[i]; ssum[i] = run; run += v; }
    off[obase + n] = run;
  }
  __syncthreads();
  int run = ssum[t];
  for (int i = lo; i < hi; i++) { off[obase + i] = run; cur[cbase + i] = run; run += cnt[cbase + i]; }
}

__global__ void k_fill(const int* __restrict__ key, const int* __restrict__ oth, int n, int edgeStrideZ,
                       int* __restrict__ cur, int curStrideZ, int* __restrict__ val, long long valStrideZ) {
  int z = blockIdx.z;
  const int* kp = key + (size_t)z * edgeStrideZ;
  const int* op = oth + (size_t)z * edgeStrideZ;
  int* cz = cur + (size_t)z * curStrideZ;
  int* vz = val + (size_t)z * valStrideZ;
  for (int i = blockIdx.x * blockDim.x + threadIdx.x; i < n; i += gridDim.x * blockDim.x) {
    int pos = atomicAdd(&cz[kp[i]], 1);
    vz[pos] = op[i];
  }
}

// ---------------- segment mean (CSR gather): one wave per dst row ----------------
__global__ __launch_bounds__(256) void k_seg_mean(
    const int* __restrict__ off, int offStrideZ,
    const int* __restrict__ val, long long valStrideZ,
    const float* __restrict__ xsrc, long long xStrideZ,
    float* __restrict__ out, long long outStrideZ, int nDst) {
  int z = blockIdx.z;
  const int* offz = off + (size_t)z * offStrideZ;
  const int* valz = val + (size_t)z * valStrideZ;
  const float* xz = xsrc + (size_t)z * xStrideZ;
  float* oz = out + (size_t)z * outStrideZ;
  int lane = threadIdx.x & 63;
  int wid = threadIdx.x >> 6;
  int wpb = blockDim.x >> 6;
  for (int d = blockIdx.x * wpb + wid; d < nDst; d += gridDim.x * wpb) {
    int b = offz[d], e = offz[d + 1];
    float ax = 0.f, ay = 0.f;
    for (int i = b; i < e; i++) {
      int nb = valz[i];
      const float2 v = *(const float2*)(xz + (size_t)nb * HC + lane * 2);
      ax += v.x; ay += v.y;
    }
    int c = e - b;
    float inv = 1.0f / (float)(c > 0 ? c : 1);
    float2 r; r.x = ax * inv; r.y = ay * inv;
    *(float2*)(oz + (size_t)d * HC + lane * 2) = r;
  }
}

// ---------------- x_dis init: disease_x @ dis_lin_w + b + disease_emb ----------------
__global__ void k_dis0(const float* __restrict__ dx, const float* __restrict__ w,
                       const float* __restrict__ b, const float* __restrict__ emb,
                       float* __restrict__ out) {
  int i = blockIdx.x;
  int j = threadIdx.x;
  float s = b[j] + emb[(size_t)i * HC + j];
  #pragma unroll
  for (int k = 0; k < 10; k++) s += dx[i * 10 + k] * w[k * HC + j];
  out[(size_t)i * HC + j] = s;
}

// ---------------- Wc = rmt_wr + sum_t rha_wr ; biasc = rmt_bl + sum_t rha_bl ----------------
__global__ void k_wc(const float* __restrict__ wr_main, const float* __restrict__ wr_t,
                     const float* __restrict__ bl_main, const float* __restrict__ bl_t,
                     float* __restrict__ Wc, float* __restrict__ biasc) {
  int i = blockIdx.x * blockDim.x + threadIdx.x;
  if (i < HC * HC) {
    float s = wr_main[i];
    #pragma unroll
    for (int t = 0; t < T_ATTR; t++) s += wr_t[(size_t)t * HC * HC + i];
    Wc[i] = s;
  }
  if (i < HC) {
    float s = bl_main[i];
    #pragma unroll
    for (int t = 0; t < T_ATTR; t++) s += bl_t[t * HC + i];
    biasc[i] = s;
  }
}

// ---------------- f32 GEMM: C[M,128] (op)= A[M,K]@B[K,128] ----------------
// mode 0: C = T + bias ; mode 1: C += T ; mode 2: D = leaky(C + T)
__global__ __launch_bounds__(256) void k_gemm128(
    const float* __restrict__ A, int lda, long long aStride,
    const float* __restrict__ B, long long bStride,
    float* __restrict__ C, long long cStride,
    const float* __restrict__ bias, int biasStride,
    float* __restrict__ D, long long dStride,
    int M, int K, int mode) {
  int z = blockIdx.z;
  A += (size_t)z * aStride;
  B += (size_t)z * bStride;
  C += (size_t)z * cStride;
  if (bias) bias += (size_t)z * biasStride;
  if (D) D += (size_t)z * dStride;
  __shared__ float As[128][16];
  __shared__ float Bs[16][128];
  int tid = threadIdx.x;
  int tx = tid & 15, ty = tid >> 4;
  int m0 = blockIdx.x * 128;
  float acc[8][8];
  #pragma unroll
  for (int i = 0; i < 8; i++)
    #pragma unroll
    for (int j = 0; j < 8; j++) acc[i][j] = 0.f;

  for (int kk = 0; kk < K; kk += 16) {
    #pragma unroll
    for (int i = 0; i < 8; i++) {
      int idx = tid + (i << 8);
      int r = idx >> 4, k = idx & 15;
      int gr = m0 + r;
      As[r][k] = (gr < M) ? A[(size_t)gr * lda + kk + k] : 0.f;
    }
    #pragma unroll
    for (int i = 0; i < 8; i++) {
      int idx = tid + (i << 8);
      int k = idx >> 7, c = idx & 127;
      Bs[k][c] = B[(size_t)(kk + k) * 128 + c];
    }
    __syncthreads();
    #pragma unroll
    for (int k = 0; k < 16; k++) {
      float a[8], b[8];
      #pragma unroll
      for (int i = 0; i < 8; i++) a[i] = As[ty + (i << 4)][k];
      #pragma unroll
      for (int j = 0; j < 8; j++) b[j] = Bs[k][tx + (j << 4)];
      #pragma unroll
      for (int i = 0; i < 8; i++)
        #pragma unroll
        for (int j = 0; j < 8; j++) acc[i][j] += a[i] * b[j];
    }
    __syncthreads();
  }
  #pragma unroll
  for (int i = 0; i < 8; i++) {
    int gr = m0 + ty + (i << 4);
    if (gr >= M) continue;
    #pragma unroll
    for (int j = 0; j < 8; j++) {
      int gc = tx + (j << 4);
      size_t o = (size_t)gr * 128 + gc;
      float v = acc[i][j];
      if (mode == 0) C[o] = v + bias[gc];
      else if (mode == 1) C[o] += v;
      else { float s = C[o] + v; D[o] = leakyf(s); }
    }
  }
}

// ---------------- fused classifier: gather + 256->64 GEMM + MLP tail ----------------
__global__ __launch_bounds__(256) void k_classifier(
    const float* __restrict__ xd, const float* __restrict__ xs,
    const int* __restrict__ esrc, const int* __restrict__ edst,
    const float* __restrict__ cw0, const float* __restrict__ cb0,
    const float* __restrict__ cw1, const float* __restrict__ cb1,
    const float* __restrict__ cw2, const float* __restrict__ cb2,
    const float* __restrict__ cw3, const float* __restrict__ cb3,
    const float* __restrict__ cw4, const float* __restrict__ cb4,
    float* __restrict__ out, int n) {
  __shared__ float As[128][16];
  __shared__ float Bs[16][64];
  __shared__ float h1s[128][65];
  __shared__ int rs[128], rd[128];
  int tid = threadIdx.x;
  int m0 = blockIdx.x * 128;
  if (tid < 128) {
    int r = m0 + tid;
    rs[tid] = (r < n) ? esrc[r] : 0;
    rd[tid] = (r < n) ? edst[r] : 0;
  }
  __syncthreads();
  int tx = tid & 15, ty = tid >> 4;
  float acc[8][4];
  #pragma unroll
  for (int i = 0; i < 8; i++)
    #pragma unroll
    for (int j = 0; j < 4; j++) acc[i][j] = 0.f;

  for (int kk = 0; kk < 256; kk += 16) {
    #pragma unroll
    for (int i = 0; i < 8; i++) {
      int idx = tid + (i << 8);
      int r = idx >> 4, k = idx & 15;
      int gk = kk + k;
      float v;
      if (gk < 128) v = xd[(size_t)rs[r] * HC + gk];
      else          v = xs[(size_t)rd[r] * HC + gk - 128];
      As[r][k] = v;
    }
    #pragma unroll
    for (int i = 0; i < 4; i++) {
      int idx = tid + (i << 8);
      int k = idx >> 6, c = idx & 63;
      Bs[k][c] = cw0[(size_t)(kk + k) * 64 + c];
    }
    __syncthreads();
    #pragma unroll
    for (int k = 0; k < 16; k++) {
      float a[8], b[4];
      #pragma unroll
      for (int i = 0; i < 8; i++) a[i] = As[ty + (i << 4)][k];
      #pragma unroll
      for (int j = 0; j < 4; j++) b[j] = Bs[k][tx + (j << 4)];
      #pragma unroll
      for (int i = 0; i < 8; i++)
        #pragma unroll
        for (int j = 0; j < 4; j++) acc[i][j] += a[i] * b[j];
    }
    __syncthreads();
  }
  #pragma unroll
  for (int i = 0; i < 8; i++) {
    int r = ty + (i << 4);
    #pragma unroll
    for (int j = 0; j < 4; j++) {
      int c = tx + (j << 4);
      h1s[r][c] = leakyf(acc[i][j] + cb0[c]);
    }
  }
  __syncthreads();
  if (tid < 128 && m0 + tid < n) {
    float h2[32];
    #pragma unroll
    for (int j = 0; j < 32; j++) {
      float s = cb1[j];
      #pragma unroll 8
      for (int k = 0; k < 64; k++) s += h1s[tid][k] * cw1[k * 32 + j];
      h2[j] = leakyf(s);
    }
    float h3[16];
    #pragma unroll
    for (int j = 0; j < 16; j++) {
      float s = cb2[j];
      #pragma unroll
      for (int k = 0; k < 32; k++) s += h2[k] * cw2[k * 16 + j];
      h3[j] = leakyf(s);
    }
    float h4[8];
    #pragma unroll
    for (int j = 0; j < 8; j++) {
      float s = cb3[j];
      #pragma unroll
      for (int k = 0; k < 16; k++) s += h3[k] * cw3[k * 8 + j];
      h4[j] = leakyf(s);
    }
    float p = cb4[0];
    #pragma unroll
    for (int k = 0; k < 8; k++) p += h4[k] * cw4[k];
    out[m0 + tid] = p;
  }
}

extern "C" void kernel_launch(void* const* d_in, const int* in_sizes, int n_in,
                              void* d_out, int out_size, void* d_ws, size_t ws_size,
                              hipStream_t stream) {
  const float* disease_x   = (const float*)d_in[0];
  const float* drug_emb    = (const float*)d_in[1];
  const float* disease_emb = (const float*)d_in[2];
  const float* attr_emb    = (const float*)d_in[3];
  const float* dis_lin_w   = (const float*)d_in[4];
  const float* dis_lin_b   = (const float*)d_in[5];
  const float* mt_wl  = (const float*)d_in[6];
  const float* mt_bl  = (const float*)d_in[7];
  const float* mt_wr  = (const float*)d_in[8];
  const float* rmt_wl = (const float*)d_in[9];
  const float* rmt_bl = (const float*)d_in[10];
  const float* rmt_wr = (const float*)d_in[11];
  const float* ha_wl  = (const float*)d_in[12];
  const float* ha_bl  = (const float*)d_in[13];
  const float* ha_wr  = (const float*)d_in[14];
  const float* rha_wl = (const float*)d_in[15];
  const float* rha_bl = (const float*)d_in[16];
  const float* rha_wr = (const float*)d_in[17];
  const float* cw0 = (const float*)d_in[18];
  const float* cb0 = (const float*)d_in[19];
  const float* cw1 = (const float*)d_in[20];
  const float* cb1 = (const float*)d_in[21];
  const float* cw2 = (const float*)d_in[22];
  const float* cb2 = (const float*)d_in[23];
  const float* cw3 = (const float*)d_in[24];
  const float* cb3 = (const float*)d_in[25];
  const float* cw4 = (const float*)d_in[26];
  const float* cb4 = (const float*)d_in[27];
  const int* mt_src = (const int*)d_in[28];
  const int* mt_dst = (const int*)d_in[29];
  const int* ha_src = (const int*)d_in[30];
  const int* ha_dst = (const int*)d_in[31];
  const int* ell_src = (const int*)d_in[32];
  const int* ell_dst = (const int*)d_in[33];
  float* out = (float*)d_out;

  // ---------- workspace carve (floats then ints), ~78.5 MB ----------
  float* fws = (float*)d_ws;
  size_t o = 0;
  float* x_drug    = fws + o; o += (size_t)N_DRUG * HC;          // 2.56M
  float* x_dis     = fws + o; o += (size_t)N_DIS * HC;           // 1.28M
  float* x_attr    = fws + o; o += (size_t)T_ATTR * N_ATTR * HC; // 2.048M
  float* acc_drug  = fws + o; o += (size_t)N_DRUG * HC;
  float* acc_dis   = fws + o; o += (size_t)N_DIS * HC;
  float* acc_attr  = fws + o; o += (size_t)T_ATTR * N_ATTR * HC;
  float* mean_tmp  = fws + o; o += (size_t)N_DRUG * HC;          // reused for all [*,128] means
  float* mean_attr = fws + o; o += (size_t)T_ATTR * N_ATTR * HC;
  float* Wc        = fws + o; o += HC * HC;
  float* biasc     = fws + o; o += HC;
  int* iws = (int*)(fws + o);
  int* cnt = iws;                       // 206000
  int* off = cnt + 206000;              // 206018
  int* cur = off + 206018;              // 206000
  int* val_mt_dst = cur + 206000;       // 500000 (stores src per edge sorted by dst)
  int* val_mt_src = val_mt_dst + E_MT;  // 500000 (stores dst per edge sorted by src)
  int* val_ha_dst = val_mt_src + E_MT;  // 8*100000 (stores drug per edge sorted by attr)
  int* val_ha_src = val_ha_dst + (size_t)T_ATTR * E_HA; // 8*100000 (stores attr per edge sorted by drug)

  dim3 b256(256);
  // ---------- CSR build ----------
  hipMemsetAsync(cnt, 0, 206000 * sizeof(int), stream);
  k_count<<<dim3((E_MT + 255) / 256, 1, 1), b256, 0, stream>>>(mt_dst, E_MT, 0, cnt + 0, 0);
  k_count<<<dim3((E_MT + 255) / 256, 1, 1), b256, 0, stream>>>(mt_src, E_MT, 0, cnt + 10000, 0);
  k_count<<<dim3((E_HA + 255) / 256, 1, T_ATTR), b256, 0, stream>>>(ha_dst, E_HA, E_HA, cnt + 30000, N_ATTR);
  k_count<<<dim3((E_HA + 255) / 256, 1, T_ATTR), b256, 0, stream>>>(ha_src, E_HA, E_HA, cnt + 46000, N_DRUG);
  k_scan<<<18, 256, 0, stream>>>(cnt, off, cur);
  k_fill<<<dim3((E_MT + 255) / 256, 1, 1), b256, 0, stream>>>(mt_dst, mt_src, E_MT, 0, cur + 0, 0, val_mt_dst, 0);
  k_fill<<<dim3((E_MT + 255) / 256, 1, 1), b256, 0, stream>>>(mt_src, mt_dst, E_MT, 0, cur + 10000, 0, val_mt_src, 0);
  k_fill<<<dim3((E_HA + 255) / 256, 1, T_ATTR), b256, 0, stream>>>(ha_dst, ha_src, E_HA, E_HA, cur + 30000, N_ATTR, val_ha_dst, E_HA);
  k_fill<<<dim3((E_HA + 255) / 256, 1, T_ATTR), b256, 0, stream>>>(ha_src, ha_dst, E_HA, E_HA, cur + 46000, N_DRUG, val_ha_src, E_HA);

  // ---------- node init ----------
  k_dis0<<<N_DIS, 128, 0, stream>>>(disease_x, dis_lin_w, dis_lin_b, disease_emb, x_dis);

  const long long ATTR_S = (long long)N_ATTR * HC;   // z-stride for attr feature slabs
  const long long W_S = HC * HC;                     // z-stride for per-t weights

  for (int l = 0; l < 2; l++) {
    const float* xd = l ? (const float*)x_drug : drug_emb;   // current drug features (read-only here)
    const float* xa = l ? (const float*)x_attr : attr_emb;   // current attr features
    const float* mt_wl_l  = mt_wl  + (size_t)l * W_S;
    const float* mt_bl_l  = mt_bl  + (size_t)l * HC;
    const float* mt_wr_l  = mt_wr  + (size_t)l * W_S;
    const float* rmt_wl_l = rmt_wl + (size_t)l * W_S;
    const float* ha_wl_l  = ha_wl  + (size_t)l * T_ATTR * W_S;
    const float* ha_bl_l  = ha_bl  + (size_t)l * T_ATTR * HC;
    const float* ha_wr_l  = ha_wr  + (size_t)l * T_ATTR * W_S;
    const float* rha_wl_l = rha_wl + (size_t)l * T_ATTR * W_S;

    // Wc = rmt_wr[l] + sum_t rha_wr[l,t]; biasc = rmt_bl[l] + sum_t rha_bl[l,t]
    k_wc<<<64, 256, 0, stream>>>(rmt_wr + (size_t)l * W_S, rha_wr + (size_t)l * T_ATTR * W_S,
                                 rmt_bl + (size_t)l * HC, rha_bl + (size_t)l * T_ATTR * HC, Wc, biasc);

    // disease <- mean(drug) @ wl + bl   (x_dis @ wr added later, in place)
    k_seg_mean<<<dim3((N_DIS + 3) / 4, 1, 1), b256, 0, stream>>>(off + 0, 0, val_mt_dst, 0, xd, 0, mean_tmp, 0, N_DIS);
    k_gemm128<<<dim3((N_DIS + 127) / 128, 1, 1), b256, 0, stream>>>(
        mean_tmp, HC, 0, mt_wl_l, 0, acc_dis, 0, mt_bl_l, 0, nullptr, 0, N_DIS, HC, 0);

    // drug <- mean(dis) @ rmt_wl + combined bias, + x_drug @ Wc
    k_seg_mean<<<dim3((N_DRUG + 3) / 4, 1, 1), b256, 0, stream>>>(off + 10001, 0, val_mt_src, 0, x_dis, 0, mean_tmp, 0, N_DRUG);
    k_gemm128<<<dim3((N_DRUG + 127) / 128, 1, 1), b256, 0, stream>>>(
        mean_tmp, HC, 0, rmt_wl_l, 0, acc_drug, 0, biasc, 0, nullptr, 0, N_DRUG, HC, 0);
    k_gemm128<<<dim3((N_DRUG + 127) / 128, 1, 1), b256, 0, stream>>>(
        xd, HC, 0, Wc, 0, acc_drug, 0, nullptr, 0, nullptr, 0, N_DRUG, HC, 1);

    // attr[t] <- mean(drug) @ ha_wl[t] + ha_bl[t]   (batched over t)
    k_seg_mean<<<dim3((N_ATTR + 3) / 4, 1, T_ATTR), b256, 0, stream>>>(
        off + 30002, 2001, val_ha_dst, E_HA, xd, 0, mean_attr, ATTR_S, N_ATTR);
    k_gemm128<<<dim3((N_ATTR + 127) / 128, 1, T_ATTR), b256, 0, stream>>>(
        mean_attr, HC, ATTR_S, ha_wl_l, W_S, acc_attr, ATTR_S, ha_bl_l, HC, nullptr, 0, N_ATTR, HC, 0);

    // drug += mean(attr[t]) @ rha_wl[t] for each t; t==7 finishes with leaky -> x_drug
    for (int t = 0; t < T_ATTR; t++) {
      k_seg_mean<<<dim3((N_DRUG + 3) / 4, 1, 1), b256, 0, stream>>>(
          off + 46010 + t * 20001, 0, val_ha_src + (size_t)t * E_HA, 0, xa + (size_t)t * ATTR_S, 0, mean_tmp, 0, N_DRUG);
      int mode = (t == 7) ? 2 : 1;
      k_gemm128<<<dim3((N_DRUG + 127) / 128, 1, 1), b256, 0, stream>>>(
          mean_tmp, HC, 0, rha_wl_l + (size_t)t * W_S, 0, acc_drug, 0, nullptr, 0,
          (t == 7) ? x_drug : nullptr, 0, N_DRUG, HC, mode);
    }

    // attr: x_attr = leaky(acc_attr + xa @ ha_wr[t])   (batched, in-place safe: row-aligned)
    k_gemm128<<<dim3((N_ATTR + 127) / 128, 1, T_ATTR), b256, 0, stream>>>(
        xa, HC, ATTR_S, ha_wr_l, W_S, acc_attr, ATTR_S, nullptr, 0, x_attr, ATTR_S, N_ATTR, HC, 2);

    // disease: x_dis = leaky(acc_dis + x_dis @ mt_wr)  (in-place safe: row-aligned)
    k_gemm128<<<dim3((N_DIS + 127) / 128, 1, 1), b256, 0, stream>>>(
        x_dis, HC, 0, mt_wr_l, 0, acc_dis, 0, nullptr, 0, x_dis, 0, N_DIS, HC, 2);
  }

  // ---------- classifier ----------
  k_classifier<<<dim3((E_LBL + 127) / 128, 1, 1), b256, 0, stream>>>(
      x_drug, x_dis, ell_src, ell_dst,
      cw0, cb0, cw1, cb1, cw2, cb2, cw3, cb3, cw4, cb4, out, E_LBL);
}

// Round 2
// 1082.444 us; speedup vs baseline: 2.2857x; 2.2857x over previous
//
#include <hip/hip_runtime.h>

#define N_DRUG 20000
#define N_DIS  10000
#define N_ATTR 2000
#define T_ATTR 8
#define E_MT   500000
#define E_HA   100000
#define E_LBL  200000
#define HC     128

__device__ __forceinline__ float leakyf(float x) { return x >= 0.f ? x : 0.01f * x; }

// ---------------- CSR build ----------------
__global__ void k_count(const int* __restrict__ idx, int n, int idxStrideZ,
                        int* __restrict__ cnt, int cntStrideZ) {
  int z = blockIdx.z;
  const int* p = idx + (size_t)z * idxStrideZ;
  int* c = cnt + (size_t)z * cntStrideZ;
  for (int i = blockIdx.x * blockDim.x + threadIdx.x; i < n; i += gridDim.x * blockDim.x)
    atomicAdd(&c[p[i]], 1);
}

// cnt layout: [0,10000) mt_dst | [10000,30000) mt_src | [30000,46000) ha_dst 8x2000 | [46000,206000) ha_src 8x20000
// off layout: 0 (10001) | 10001 (20001) | 30002 + t*2001 | 46010 + t*20001   (total 206018)
__global__ void k_scan(const int* __restrict__ cnt, int* __restrict__ off, int* __restrict__ cur) {
  int id = blockIdx.x;
  int cbase, obase, n;
  if (id == 0)      { cbase = 0;      obase = 0;      n = N_DIS; }
  else if (id == 1) { cbase = 10000;  obase = 10001;  n = N_DRUG; }
  else if (id < 10) { int t = id - 2;  cbase = 30000 + t * 2000;  obase = 30002 + t * 2001;  n = N_ATTR; }
  else              { int t = id - 10; cbase = 46000 + t * 20000; obase = 46010 + t * 20001; n = N_DRUG; }
  __shared__ int ssum[256];
  int t = threadIdx.x;
  int per = (n + 255) >> 8;
  int lo = t * per; if (lo > n) lo = n;
  int hi = lo + per; if (hi > n) hi = n;
  int s = 0;
  for (int i = lo; i < hi; i++) s += cnt[cbase + i];
  ssum[t] = s;
  __syncthreads();
  if (t == 0) {
    int run = 0;
    for (int i = 0; i < 256; i++) { int v = ssum[i]; ssum[i] = run; run += v; }
    off[obase + n] = run;
  }
  __syncthreads();
  int run = ssum[t];
  for (int i = lo; i < hi; i++) { off[obase + i] = run; cur[cbase + i] = run; run += cnt[cbase + i]; }
}

__global__ void k_fill(const int* __restrict__ key, const int* __restrict__ oth, int n, int edgeStrideZ,
                       int* __restrict__ cur, int curStrideZ, int* __restrict__ val, long long valStrideZ) {
  int z = blockIdx.z;
  const int* kp = key + (size_t)z * edgeStrideZ;
  const int* op = oth + (size_t)z * edgeStrideZ;
  int* cz = cur + (size_t)z * curStrideZ;
  int* vz = val + (size_t)z * valStrideZ;
  for (int i = blockIdx.x * blockDim.x + threadIdx.x; i < n; i += gridDim.x * blockDim.x) {
    int pos = atomicAdd(&cz[kp[i]], 1);
    vz[pos] = op[i];
  }
}

// ---------------- x_dis init ----------------
__global__ void k_dis0(const float* __restrict__ dx, const float* __restrict__ w,
                       const float* __restrict__ b, const float* __restrict__ emb,
                       float* __restrict__ out) {
  int i = blockIdx.x;
  int j = threadIdx.x;
  float s = b[j] + emb[(size_t)i * HC + j];
  #pragma unroll
  for (int k = 0; k < 10; k++) s += dx[i * 10 + k] * w[k * HC + j];
  out[(size_t)i * HC + j] = s;
}

// ---------------- Wc = rmt_wr + sum_t rha_wr ; biasc = rmt_bl + sum_t rha_bl ----------------
__global__ void k_wc(const float* __restrict__ wr_main, const float* __restrict__ wr_t,
                     const float* __restrict__ bl_main, const float* __restrict__ bl_t,
                     float* __restrict__ Wc, float* __restrict__ biasc) {
  int i = blockIdx.x * blockDim.x + threadIdx.x;
  if (i < HC * HC) {
    float s = wr_main[i];
    #pragma unroll
    for (int t = 0; t < T_ATTR; t++) s += wr_t[(size_t)t * HC * HC + i];
    Wc[i] = s;
  }
  if (i < HC) {
    float s = bl_main[i];
    #pragma unroll
    for (int t = 0; t < T_ATTR; t++) s += bl_t[t * HC + i];
    biasc[i] = s;
  }
}

// ---------------- unroll-4 gather accumulate ----------------
__device__ __forceinline__ void gacc(const float* __restrict__ X, const int* __restrict__ val,
                                     int b, int e, int lane2, float& ax, float& ay) {
  int i = b;
  for (; i + 4 <= e; i += 4) {
    int n0 = val[i], n1 = val[i + 1], n2 = val[i + 2], n3 = val[i + 3];
    float2 v0 = *(const float2*)(X + (size_t)n0 * HC + lane2);
    float2 v1 = *(const float2*)(X + (size_t)n1 * HC + lane2);
    float2 v2 = *(const float2*)(X + (size_t)n2 * HC + lane2);
    float2 v3 = *(const float2*)(X + (size_t)n3 * HC + lane2);
    ax += v0.x + v1.x + v2.x + v3.x;
    ay += v0.y + v1.y + v2.y + v3.y;
  }
  for (; i < e; i++) {
    int n = val[i];
    float2 v = *(const float2*)(X + (size_t)n * HC + lane2);
    ax += v.x; ay += v.y;
  }
}

// ---------------- mega segment-mean: all gathers of one layer ----------------
// wave w: [0,10000) m2dis | [10000,30000) drug merged (mt + 8*ha) | [30000,46000) m2a
__global__ __launch_bounds__(256) void k_seg_mega(
    const int* __restrict__ off,
    const int* __restrict__ vmt_dst, const int* __restrict__ vmt_src,
    const int* __restrict__ vha_dst, const int* __restrict__ vha_src,
    const float* __restrict__ xd, const float* __restrict__ Ydis,
    const float* __restrict__ Yattr,
    float* __restrict__ m2dis, float* __restrict__ accd, float* __restrict__ m2a) {
  int lane2 = (threadIdx.x & 63) * 2;
  int w = blockIdx.x * 4 + (threadIdx.x >> 6);
  if (w < N_DIS) {
    int d = w;
    int b = off[d], e = off[d + 1];
    float ax = 0.f, ay = 0.f;
    gacc(xd, vmt_dst, b, e, lane2, ax, ay);
    int c = e - b;
    float inv = 1.f / (float)(c > 0 ? c : 1);
    *(float2*)(m2dis + (size_t)d * HC + lane2) = make_float2(ax * inv, ay * inv);
  } else if (w < N_DIS + N_DRUG) {
    int d = w - N_DIS;
    float sx = 0.f, sy = 0.f;
    {
      int b = off[10001 + d], e = off[10001 + d + 1];
      float ax = 0.f, ay = 0.f;
      gacc(Ydis, vmt_src, b, e, lane2, ax, ay);
      int c = e - b;
      float inv = 1.f / (float)(c > 0 ? c : 1);
      sx += ax * inv; sy += ay * inv;
    }
    for (int t = 0; t < T_ATTR; t++) {
      int ob = 46010 + t * 20001;
      int b = off[ob + d], e = off[ob + d + 1];
      float ax = 0.f, ay = 0.f;
      gacc(Yattr + (size_t)t * N_ATTR * HC, vha_src + (size_t)t * E_HA, b, e, lane2, ax, ay);
      int c = e - b;
      float inv = 1.f / (float)(c > 0 ? c : 1);
      sx += ax * inv; sy += ay * inv;
    }
    *(float2*)(accd + (size_t)d * HC + lane2) = make_float2(sx, sy);
  } else {
    int idx = w - (N_DIS + N_DRUG);
    int t = idx / N_ATTR, r = idx - t * N_ATTR;
    int ob = 30002 + t * 2001;
    int b = off[ob + r], e = off[ob + r + 1];
    float ax = 0.f, ay = 0.f;
    gacc(xd, vha_dst + (size_t)t * E_HA, b, e, lane2, ax, ay);
    int c = e - b;
    float inv = 1.f / (float)(c > 0 ? c : 1);
    *(float2*)(m2a + ((size_t)t * N_ATTR + r) * HC + lane2) = make_float2(ax * inv, ay * inv);
  }
}

// ---------------- generalized batched GEMM ----------------
// D = [leaky]( A1@B1 [+ A2@B2] [+ ACC] [+ bias] ), all [M,128] row-major, B [128,128]
struct GemmJob {
  const float* A1; const float* B1;
  const float* A2; const float* B2;
  const float* bias; const float* ACC;
  float* D;
  int M; int leaky;
};
struct GemmJobs { GemmJob j[10]; };

__global__ __launch_bounds__(256) void k_gemm_multi(GemmJobs jobs) {
  GemmJob jb = jobs.j[blockIdx.z];
  int m0 = blockIdx.x * 64;
  if (m0 >= jb.M) return;
  __shared__ float As[16][68];    // k-major, padded
  __shared__ float Bs[16][132];
  int tid = threadIdx.x;
  int tx = tid & 31, ty = tid >> 5;   // cols tx*4..+3, rows ty*8..+7
  float acc[8][4];
  #pragma unroll
  for (int i = 0; i < 8; i++)
    #pragma unroll
    for (int j = 0; j < 4; j++) acc[i][j] = 0.f;

  int K = jb.A2 ? 256 : 128;
  for (int kk = 0; kk < K; kk += 16) {
    const float* A = (kk < 128) ? jb.A1 : jb.A2;
    const float* B = (kk < 128) ? jb.B1 : jb.B2;
    int kb = kk & 127;
    {
      int r = tid >> 2, kq = (tid & 3) * 4;
      int gr = m0 + r;
      float4 v = make_float4(0.f, 0.f, 0.f, 0.f);
      if (gr < jb.M) v = *(const float4*)(A + (size_t)gr * HC + kb + kq);
      As[kq + 0][r] = v.x; As[kq + 1][r] = v.y; As[kq + 2][r] = v.z; As[kq + 3][r] = v.w;
    }
    #pragma unroll
    for (int i = 0; i < 2; i++) {
      int idx = i * 256 + tid;
      int k = idx >> 5, c = (idx & 31) * 4;
      *(float4*)&Bs[k][c] = *(const float4*)(B + (size_t)(kb + k) * HC + c);
    }
    __syncthreads();
    #pragma unroll
    for (int k = 0; k < 16; k++) {
      float4 a0 = *(const float4*)&As[k][ty * 8];
      float4 a1 = *(const float4*)&As[k][ty * 8 + 4];
      float4 bv = *(const float4*)&Bs[k][tx * 4];
      float av[8] = {a0.x, a0.y, a0.z, a0.w, a1.x, a1.y, a1.z, a1.w};
      float bb[4] = {bv.x, bv.y, bv.z, bv.w};
      #pragma unroll
      for (int i = 0; i < 8; i++)
        #pragma unroll
        for (int j = 0; j < 4; j++) acc[i][j] += av[i] * bb[j];
    }
    __syncthreads();
  }

  int c0 = tx * 4;
  float4 bs = make_float4(0.f, 0.f, 0.f, 0.f);
  if (jb.bias) bs = *(const float4*)(jb.bias + c0);
  #pragma unroll
  for (int i = 0; i < 8; i++) {
    int gr = m0 + ty * 8 + i;
    if (gr >= jb.M) break;
    float r0 = acc[i][0] + bs.x, r1 = acc[i][1] + bs.y, r2 = acc[i][2] + bs.z, r3 = acc[i][3] + bs.w;
    if (jb.ACC) {
      float4 ac = *(const float4*)(jb.ACC + (size_t)gr * HC + c0);
      r0 += ac.x; r1 += ac.y; r2 += ac.z; r3 += ac.w;
    }
    if (jb.leaky) { r0 = leakyf(r0); r1 = leakyf(r1); r2 = leakyf(r2); r3 = leakyf(r3); }
    float4 rv = make_float4(r0, r1, r2, r3);
    *(float4*)(jb.D + (size_t)gr * HC + c0) = rv;
  }
}

// ---------------- fused classifier ----------------
__global__ __launch_bounds__(256) void k_classifier(
    const float* __restrict__ xd, const float* __restrict__ xs,
    const int* __restrict__ esrc, const int* __restrict__ edst,
    const float* __restrict__ cw0, const float* __restrict__ cb0,
    const float* __restrict__ cw1, const float* __restrict__ cb1,
    const float* __restrict__ cw2, const float* __restrict__ cb2,
    const float* __restrict__ cw3, const float* __restrict__ cb3,
    const float* __restrict__ cw4, const float* __restrict__ cb4,
    float* __restrict__ out, int n) {
  __shared__ union U {
    struct { float As[128][16]; float Bs[16][64]; } s;
    float h1s[128][65];
  } u;
  __shared__ int rs[128], rd[128];
  int tid = threadIdx.x;
  int m0 = blockIdx.x * 128;
  if (tid < 128) {
    int r = m0 + tid;
    rs[tid] = (r < n) ? esrc[r] : 0;
    rd[tid] = (r < n) ? edst[r] : 0;
  }
  __syncthreads();
  int tx = tid & 15, ty = tid >> 4;
  float acc[8][4];
  #pragma unroll
  for (int i = 0; i < 8; i++)
    #pragma unroll
    for (int j = 0; j < 4; j++) acc[i][j] = 0.f;

  for (int kk = 0; kk < 256; kk += 16) {
    #pragma unroll
    for (int i = 0; i < 8; i++) {
      int idx = tid + (i << 8);
      int r = idx >> 4, k = idx & 15;
      int gk = kk + k;
      float v;
      if (gk < 128) v = xd[(size_t)rs[r] * HC + gk];
      else          v = xs[(size_t)rd[r] * HC + gk - 128];
      u.s.As[r][k] = v;
    }
    #pragma unroll
    for (int i = 0; i < 4; i++) {
      int idx = tid + (i << 8);
      int k = idx >> 6, c = idx & 63;
      u.s.Bs[k][c] = cw0[(size_t)(kk + k) * 64 + c];
    }
    __syncthreads();
    #pragma unroll
    for (int k = 0; k < 16; k++) {
      float a[8], b[4];
      #pragma unroll
      for (int i = 0; i < 8; i++) a[i] = u.s.As[ty + (i << 4)][k];
      #pragma unroll
      for (int j = 0; j < 4; j++) b[j] = u.s.Bs[k][tx + (j << 4)];
      #pragma unroll
      for (int i = 0; i < 8; i++)
        #pragma unroll
        for (int j = 0; j < 4; j++) acc[i][j] += a[i] * b[j];
    }
    __syncthreads();
  }
  #pragma unroll
  for (int i = 0; i < 8; i++) {
    int r = ty + (i << 4);
    #pragma unroll
    for (int j = 0; j < 4; j++) {
      int c = tx + (j << 4);
      u.h1s[r][c] = leakyf(acc[i][j] + cb0[c]);
    }
  }
  __syncthreads();
  if (tid < 128 && m0 + tid < n) {
    float h2[32];
    #pragma unroll
    for (int j = 0; j < 32; j++) {
      float s = cb1[j];
      #pragma unroll 8
      for (int k = 0; k < 64; k++) s += u.h1s[tid][k] * cw1[k * 32 + j];
      h2[j] = leakyf(s);
    }
    float h3[16];
    #pragma unroll
    for (int j = 0; j < 16; j++) {
      float s = cb2[j];
      #pragma unroll
      for (int k = 0; k < 32; k++) s += h2[k] * cw2[k * 16 + j];
      h3[j] = leakyf(s);
    }
    float h4[8];
    #pragma unroll
    for (int j = 0; j < 8; j++) {
      float s = cb3[j];
      #pragma unroll
      for (int k = 0; k < 16; k++) s += h3[k] * cw3[k * 8 + j];
      h4[j] = leakyf(s);
    }
    float p = cb4[0];
    #pragma unroll
    for (int k = 0; k < 8; k++) p += h4[k] * cw4[k];
    out[m0 + tid] = p;
  }
}

extern "C" void kernel_launch(void* const* d_in, const int* in_sizes, int n_in,
                              void* d_out, int out_size, void* d_ws, size_t ws_size,
                              hipStream_t stream) {
  const float* disease_x   = (const float*)d_in[0];
  const float* drug_emb    = (const float*)d_in[1];
  const float* disease_emb = (const float*)d_in[2];
  const float* attr_emb    = (const float*)d_in[3];
  const float* dis_lin_w   = (const float*)d_in[4];
  const float* dis_lin_b   = (const float*)d_in[5];
  const float* mt_wl  = (const float*)d_in[6];
  const float* mt_bl  = (const float*)d_in[7];
  const float* mt_wr  = (const float*)d_in[8];
  const float* rmt_wl = (const float*)d_in[9];
  const float* rmt_bl = (const float*)d_in[10];
  const float* rmt_wr = (const float*)d_in[11];
  const float* ha_wl  = (const float*)d_in[12];
  const float* ha_bl  = (const float*)d_in[13];
  const float* ha_wr  = (const float*)d_in[14];
  const float* rha_wl = (const float*)d_in[15];
  const float* rha_bl = (const float*)d_in[16];
  const float* rha_wr = (const float*)d_in[17];
  const float* cw0 = (const float*)d_in[18];
  const float* cb0 = (const float*)d_in[19];
  const float* cw1 = (const float*)d_in[20];
  const float* cb1 = (const float*)d_in[21];
  const float* cw2 = (const float*)d_in[22];
  const float* cb2 = (const float*)d_in[23];
  const float* cw3 = (const float*)d_in[24];
  const float* cb3 = (const float*)d_in[25];
  const float* cw4 = (const float*)d_in[26];
  const float* cb4 = (const float*)d_in[27];
  const int* mt_src = (const int*)d_in[28];
  const int* mt_dst = (const int*)d_in[29];
  const int* ha_src = (const int*)d_in[30];
  const int* ha_dst = (const int*)d_in[31];
  const int* ell_src = (const int*)d_in[32];
  const int* ell_dst = (const int*)d_in[33];
  float* out = (float*)d_out;

  const long long ATTR_S = (long long)N_ATTR * HC;
  const long long W_S = HC * HC;

  // ---------- workspace carve ----------
  float* fws = (float*)d_ws;
  size_t o = 0;
  float* x_drug = fws + o; o += (size_t)N_DRUG * HC;
  float* x_dis  = fws + o; o += (size_t)N_DIS * HC;
  float* x_attr = fws + o; o += (size_t)T_ATTR * N_ATTR * HC;
  float* Ydis   = fws + o; o += (size_t)N_DIS * HC;
  float* Yattr  = fws + o; o += (size_t)T_ATTR * N_ATTR * HC;
  float* m2dis  = fws + o; o += (size_t)N_DIS * HC;
  float* m2a    = fws + o; o += (size_t)T_ATTR * N_ATTR * HC;
  float* accd   = fws + o; o += (size_t)N_DRUG * HC;
  float* Wc     = fws + o; o += HC * HC;
  float* biasc  = fws + o; o += HC;
  int* iws = (int*)(fws + o);
  int* cnt = iws;
  int* off = cnt + 206000;
  int* cur = off + 206018;
  int* val_mt_dst = cur + 206000;
  int* val_mt_src = val_mt_dst + E_MT;
  int* val_ha_dst = val_mt_src + E_MT;
  int* val_ha_src = val_ha_dst + (size_t)T_ATTR * E_HA;

  dim3 b256(256);
  // ---------- CSR build ----------
  hipMemsetAsync(cnt, 0, 206000 * sizeof(int), stream);
  k_count<<<dim3((E_MT + 255) / 256, 1, 1), b256, 0, stream>>>(mt_dst, E_MT, 0, cnt + 0, 0);
  k_count<<<dim3((E_MT + 255) / 256, 1, 1), b256, 0, stream>>>(mt_src, E_MT, 0, cnt + 10000, 0);
  k_count<<<dim3((E_HA + 255) / 256, 1, T_ATTR), b256, 0, stream>>>(ha_dst, E_HA, E_HA, cnt + 30000, N_ATTR);
  k_count<<<dim3((E_HA + 255) / 256, 1, T_ATTR), b256, 0, stream>>>(ha_src, E_HA, E_HA, cnt + 46000, N_DRUG);
  k_scan<<<18, 256, 0, stream>>>(cnt, off, cur);
  k_fill<<<dim3((E_MT + 255) / 256, 1, 1), b256, 0, stream>>>(mt_dst, mt_src, E_MT, 0, cur + 0, 0, val_mt_dst, 0);
  k_fill<<<dim3((E_MT + 255) / 256, 1, 1), b256, 0, stream>>>(mt_src, mt_dst, E_MT, 0, cur + 10000, 0, val_mt_src, 0);
  k_fill<<<dim3((E_HA + 255) / 256, 1, T_ATTR), b256, 0, stream>>>(ha_dst, ha_src, E_HA, E_HA, cur + 30000, N_ATTR, val_ha_dst, E_HA);
  k_fill<<<dim3((E_HA + 255) / 256, 1, T_ATTR), b256, 0, stream>>>(ha_src, ha_dst, E_HA, E_HA, cur + 46000, N_DRUG, val_ha_src, E_HA);

  // ---------- node init ----------
  k_dis0<<<N_DIS, 128, 0, stream>>>(disease_x, dis_lin_w, dis_lin_b, disease_emb, x_dis);

  for (int l = 0; l < 2; l++) {
    const float* xd = l ? (const float*)x_drug : drug_emb;
    const float* xa = l ? (const float*)x_attr : attr_emb;
    const float* mt_wl_l  = mt_wl  + (size_t)l * W_S;
    const float* mt_bl_l  = mt_bl  + (size_t)l * HC;
    const float* mt_wr_l  = mt_wr  + (size_t)l * W_S;
    const float* rmt_wl_l = rmt_wl + (size_t)l * W_S;
    const float* ha_wl_l  = ha_wl  + (size_t)l * T_ATTR * W_S;
    const float* ha_bl_l  = ha_bl  + (size_t)l * T_ATTR * HC;
    const float* ha_wr_l  = ha_wr  + (size_t)l * T_ATTR * W_S;
    const float* rha_wl_l = rha_wl + (size_t)l * T_ATTR * W_S;

    k_wc<<<64, 256, 0, stream>>>(rmt_wr + (size_t)l * W_S, rha_wr + (size_t)l * T_ATTR * W_S,
                                 rmt_bl + (size_t)l * HC, rha_bl + (size_t)l * T_ATTR * HC, Wc, biasc);

    // pre-transform GEMMs on the small side: Ydis = x_dis@rmt_wl, Yattr_t = x_attr_t@rha_wl_t
    {
      GemmJobs J{};
      J.j[0] = {x_dis, rmt_wl_l, nullptr, nullptr, nullptr, nullptr, Ydis, N_DIS, 0};
      for (int t = 0; t < T_ATTR; t++)
        J.j[1 + t] = {xa + (size_t)t * ATTR_S, rha_wl_l + (size_t)t * W_S,
                      nullptr, nullptr, nullptr, nullptr, Yattr + (size_t)t * ATTR_S, N_ATTR, 0};
      k_gemm_multi<<<dim3((N_DIS + 63) / 64, 1, 9), b256, 0, stream>>>(J);
    }

    // all gathers of this layer
    k_seg_mega<<<dim3((46000 + 3) / 4, 1, 1), b256, 0, stream>>>(
        off, val_mt_dst, val_mt_src, val_ha_dst, val_ha_src,
        xd, Ydis, Yattr, m2dis, accd, m2a);

    // combine GEMMs (fused bias + leaky, in-place row-aligned writes)
    {
      GemmJobs J{};
      J.j[0] = {xd, Wc, nullptr, nullptr, biasc, accd, x_drug, N_DRUG, 1};
      J.j[1] = {m2dis, mt_wl_l, x_dis, mt_wr_l, mt_bl_l, nullptr, x_dis, N_DIS, 1};
      for (int t = 0; t < T_ATTR; t++)
        J.j[2 + t] = {m2a + (size_t)t * ATTR_S, ha_wl_l + (size_t)t * W_S,
                      xa + (size_t)t * ATTR_S, ha_wr_l + (size_t)t * W_S,
                      ha_bl_l + (size_t)t * HC, nullptr, x_attr + (size_t)t * ATTR_S, N_ATTR, 1};
      k_gemm_multi<<<dim3((N_DRUG + 63) / 64, 1, 10), b256, 0, stream>>>(J);
    }
  }

  // ---------- classifier ----------
  k_classifier<<<dim3((E_LBL + 127) / 128, 1, 1), b256, 0, stream>>>(
      x_drug, x_dis, ell_src, ell_dst,
      cw0, cb0, cw1, cb1, cw2, cb2, cw3, cb3, cw4, cb4, out, E_LBL);
}

// Round 3
// 829.694 us; speedup vs baseline: 2.9821x; 1.3046x over previous
//
#include <hip/hip_runtime.h>

#define N_DRUG 20000
#define N_DIS  10000
#define N_ATTR 2000
#define T_ATTR 8
#define E_MT   500000
#define E_HA   100000
#define E_LBL  200000
#define HC     128

__device__ __forceinline__ float leakyf(float x) { return x >= 0.f ? x : 0.01f * x; }

// ---------------- CSR build (merged) ----------------
// cnt layout: [0,10000) mt_dst | [10000,30000) mt_src | [30000,46000) ha_dst 8x2000 | [46000,206000) ha_src 8x20000
// off layout: 0 (10001) | 10001 (20001) | 30002 + t*2001 | 46010 + t*20001   (total 206018)
__global__ void k_count_all(const int* __restrict__ mt_src, const int* __restrict__ mt_dst,
                            const int* __restrict__ ha_src, const int* __restrict__ ha_dst,
                            int* __restrict__ cnt) {
  int z = blockIdx.z;
  const int* p; int n; int* c;
  if (z == 0)      { p = mt_dst; n = E_MT; c = cnt; }
  else if (z == 1) { p = mt_src; n = E_MT; c = cnt + 10000; }
  else if (z < 10) { int t = z - 2;  p = ha_dst + (size_t)t * E_HA; n = E_HA; c = cnt + 30000 + t * 2000; }
  else             { int t = z - 10; p = ha_src + (size_t)t * E_HA; n = E_HA; c = cnt + 46000 + t * 20000; }
  for (int i = blockIdx.x * blockDim.x + threadIdx.x; i < n; i += gridDim.x * blockDim.x)
    atomicAdd(&c[p[i]], 1);
}

__global__ void k_scan(const int* __restrict__ cnt, int* __restrict__ off, int* __restrict__ cur) {
  int id = blockIdx.x;
  int cbase, obase, n;
  if (id == 0)      { cbase = 0;      obase = 0;      n = N_DIS; }
  else if (id == 1) { cbase = 10000;  obase = 10001;  n = N_DRUG; }
  else if (id < 10) { int t = id - 2;  cbase = 30000 + t * 2000;  obase = 30002 + t * 2001;  n = N_ATTR; }
  else              { int t = id - 10; cbase = 46000 + t * 20000; obase = 46010 + t * 20001; n = N_DRUG; }
  __shared__ int ssum[256];
  int t = threadIdx.x;
  int per = (n + 255) >> 8;
  int lo = t * per; if (lo > n) lo = n;
  int hi = lo + per; if (hi > n) hi = n;
  int s = 0;
  for (int i = lo; i < hi; i++) s += cnt[cbase + i];
  ssum[t] = s;
  __syncthreads();
  if (t == 0) {
    int run = 0;
    for (int i = 0; i < 256; i++) { int v = ssum[i]; ssum[i] = run; run += v; }
    off[obase + n] = run;
  }
  __syncthreads();
  int run = ssum[t];
  for (int i = lo; i < hi; i++) { off[obase + i] = run; cur[cbase + i] = run; run += cnt[cbase + i]; }
}

__global__ void k_fill_all(const int* __restrict__ mt_src, const int* __restrict__ mt_dst,
                           const int* __restrict__ ha_src, const int* __restrict__ ha_dst,
                           int* __restrict__ cur,
                           int* __restrict__ val_mt_dst, int* __restrict__ val_mt_src,
                           int* __restrict__ val_ha_dst, int* __restrict__ val_ha_src) {
  int z = blockIdx.z;
  const int* kp; const int* op; int n; int* cz; int* vz;
  if (z == 0)      { kp = mt_dst; op = mt_src; n = E_MT; cz = cur; vz = val_mt_dst; }
  else if (z == 1) { kp = mt_src; op = mt_dst; n = E_MT; cz = cur + 10000; vz = val_mt_src; }
  else if (z < 10) { int t = z - 2;  kp = ha_dst + (size_t)t * E_HA; op = ha_src + (size_t)t * E_HA; n = E_HA;
                     cz = cur + 30000 + t * 2000;  vz = val_ha_dst + (size_t)t * E_HA; }
  else             { int t = z - 10; kp = ha_src + (size_t)t * E_HA; op = ha_dst + (size_t)t * E_HA; n = E_HA;
                     cz = cur + 46000 + t * 20000; vz = val_ha_src + (size_t)t * E_HA; }
  for (int i = blockIdx.x * blockDim.x + threadIdx.x; i < n; i += gridDim.x * blockDim.x) {
    int pos = atomicAdd(&cz[kp[i]], 1);
    vz[pos] = op[i];
  }
}

// ---------------- x_dis init ----------------
__global__ void k_dis0(const float* __restrict__ dx, const float* __restrict__ w,
                       const float* __restrict__ b, const float* __restrict__ emb,
                       float* __restrict__ out) {
  int i = blockIdx.x;
  int j = threadIdx.x;
  float s = b[j] + emb[(size_t)i * HC + j];
  #pragma unroll
  for (int k = 0; k < 10; k++) s += dx[i * 10 + k] * w[k * HC + j];
  out[(size_t)i * HC + j] = s;
}

// ---------------- Wc = rmt_wr + sum_t rha_wr ; biasc = rmt_bl + sum_t rha_bl ----------------
__global__ void k_wc(const float* __restrict__ wr_main, const float* __restrict__ wr_t,
                     const float* __restrict__ bl_main, const float* __restrict__ bl_t,
                     float* __restrict__ Wc, float* __restrict__ biasc) {
  int i = blockIdx.x * blockDim.x + threadIdx.x;
  if (i < HC * HC) {
    float s = wr_main[i];
    #pragma unroll
    for (int t = 0; t < T_ATTR; t++) s += wr_t[(size_t)t * HC * HC + i];
    Wc[i] = s;
  }
  if (i < HC) {
    float s = bl_main[i];
    #pragma unroll
    for (int t = 0; t < T_ATTR; t++) s += bl_t[t * HC + i];
    biasc[i] = s;
  }
}

// ---------------- unroll-8 gather accumulate ----------------
__device__ __forceinline__ void gacc(const float* __restrict__ X, const int* __restrict__ val,
                                     int b, int e, int lane2, float& ax, float& ay) {
  int i = b;
  for (; i + 8 <= e; i += 8) {
    float2 v[8];
    #pragma unroll
    for (int q = 0; q < 8; q++) {
      int n = val[i + q];
      v[q] = *(const float2*)(X + (size_t)n * HC + lane2);
    }
    #pragma unroll
    for (int q = 0; q < 8; q++) { ax += v[q].x; ay += v[q].y; }
  }
  for (; i < e; i++) {
    int n = val[i];
    float2 v = *(const float2*)(X + (size_t)n * HC + lane2);
    ax += v.x; ay += v.y;
  }
}

// ---------------- mega segment-mean: all gathers of one layer ----------------
// wave w: [0,10000) m2dis | [10000,30000) drug merged (mt + 8*ha) | [30000,46000) m2a
__global__ __launch_bounds__(256) void k_seg_mega(
    const int* __restrict__ off,
    const int* __restrict__ vmt_dst, const int* __restrict__ vmt_src,
    const int* __restrict__ vha_dst, const int* __restrict__ vha_src,
    const float* __restrict__ xd, const float* __restrict__ Ydis,
    const float* __restrict__ Yattr,
    float* __restrict__ m2dis, float* __restrict__ accd, float* __restrict__ m2a) {
  int lane2 = (threadIdx.x & 63) * 2;
  int w = blockIdx.x * 4 + (threadIdx.x >> 6);
  if (w < N_DIS) {
    int d = w;
    int b = off[d], e = off[d + 1];
    float ax = 0.f, ay = 0.f;
    gacc(xd, vmt_dst, b, e, lane2, ax, ay);
    int c = e - b;
    float inv = 1.f / (float)(c > 0 ? c : 1);
    *(float2*)(m2dis + (size_t)d * HC + lane2) = make_float2(ax * inv, ay * inv);
  } else if (w < N_DIS + N_DRUG) {
    int d = w - N_DIS;
    float sx = 0.f, sy = 0.f;
    {
      int b = off[10001 + d], e = off[10001 + d + 1];
      float ax = 0.f, ay = 0.f;
      gacc(Ydis, vmt_src, b, e, lane2, ax, ay);
      int c = e - b;
      float inv = 1.f / (float)(c > 0 ? c : 1);
      sx += ax * inv; sy += ay * inv;
    }
    for (int t = 0; t < T_ATTR; t++) {
      int ob = 46010 + t * 20001;
      int b = off[ob + d], e = off[ob + d + 1];
      float ax = 0.f, ay = 0.f;
      gacc(Yattr + (size_t)t * N_ATTR * HC, vha_src + (size_t)t * E_HA, b, e, lane2, ax, ay);
      int c = e - b;
      float inv = 1.f / (float)(c > 0 ? c : 1);
      sx += ax * inv; sy += ay * inv;
    }
    *(float2*)(accd + (size_t)d * HC + lane2) = make_float2(sx, sy);
  } else {
    int idx = w - (N_DIS + N_DRUG);
    int t = idx / N_ATTR, r = idx - t * N_ATTR;
    int ob = 30002 + t * 2001;
    int b = off[ob + r], e = off[ob + r + 1];
    float ax = 0.f, ay = 0.f;
    gacc(xd, vha_dst + (size_t)t * E_HA, b, e, lane2, ax, ay);
    int c = e - b;
    float inv = 1.f / (float)(c > 0 ? c : 1);
    *(float2*)(m2a + ((size_t)t * N_ATTR + r) * HC + lane2) = make_float2(ax * inv, ay * inv);
  }
}

// ---------------- generalized batched GEMM ----------------
// D = [leaky]( A1@B1 [+ A2@B2] [+ ACC] [+ bias] ), all [M,128] row-major, B [128,128]
struct GemmJob {
  const float* A1; const float* B1;
  const float* A2; const float* B2;
  const float* bias; const float* ACC;
  float* D;
  int M; int leaky;
};
struct GemmJobs { GemmJob j[10]; };

__global__ __launch_bounds__(256) void k_gemm_multi(GemmJobs jobs) {
  GemmJob jb = jobs.j[blockIdx.z];
  int m0 = blockIdx.x * 64;
  if (m0 >= jb.M) return;
  __shared__ float As[16][68];    // k-major, padded
  __shared__ float Bs[16][132];
  int tid = threadIdx.x;
  int tx = tid & 31, ty = tid >> 5;   // cols tx*4..+3, rows ty*8..+7
  float acc[8][4];
  #pragma unroll
  for (int i = 0; i < 8; i++)
    #pragma unroll
    for (int j = 0; j < 4; j++) acc[i][j] = 0.f;

  int K = jb.A2 ? 256 : 128;
  for (int kk = 0; kk < K; kk += 16) {
    const float* A = (kk < 128) ? jb.A1 : jb.A2;
    const float* B = (kk < 128) ? jb.B1 : jb.B2;
    int kb = kk & 127;
    {
      int r = tid >> 2, kq = (tid & 3) * 4;
      int gr = m0 + r;
      float4 v = make_float4(0.f, 0.f, 0.f, 0.f);
      if (gr < jb.M) v = *(const float4*)(A + (size_t)gr * HC + kb + kq);
      As[kq + 0][r] = v.x; As[kq + 1][r] = v.y; As[kq + 2][r] = v.z; As[kq + 3][r] = v.w;
    }
    #pragma unroll
    for (int i = 0; i < 2; i++) {
      int idx = i * 256 + tid;
      int k = idx >> 5, c = (idx & 31) * 4;
      *(float4*)&Bs[k][c] = *(const float4*)(B + (size_t)(kb + k) * HC + c);
    }
    __syncthreads();
    #pragma unroll
    for (int k = 0; k < 16; k++) {
      float4 a0 = *(const float4*)&As[k][ty * 8];
      float4 a1 = *(const float4*)&As[k][ty * 8 + 4];
      float4 bv = *(const float4*)&Bs[k][tx * 4];
      float av[8] = {a0.x, a0.y, a0.z, a0.w, a1.x, a1.y, a1.z, a1.w};
      float bb[4] = {bv.x, bv.y, bv.z, bv.w};
      #pragma unroll
      for (int i = 0; i < 8; i++)
        #pragma unroll
        for (int j = 0; j < 4; j++) acc[i][j] += av[i] * bb[j];
    }
    __syncthreads();
  }

  int c0 = tx * 4;
  float4 bs = make_float4(0.f, 0.f, 0.f, 0.f);
  if (jb.bias) bs = *(const float4*)(jb.bias + c0);
  #pragma unroll
  for (int i = 0; i < 8; i++) {
    int gr = m0 + ty * 8 + i;
    if (gr >= jb.M) break;
    float r0 = acc[i][0] + bs.x, r1 = acc[i][1] + bs.y, r2 = acc[i][2] + bs.z, r3 = acc[i][3] + bs.w;
    if (jb.ACC) {
      float4 ac = *(const float4*)(jb.ACC + (size_t)gr * HC + c0);
      r0 += ac.x; r1 += ac.y; r2 += ac.z; r3 += ac.w;
    }
    if (jb.leaky) { r0 = leakyf(r0); r1 = leakyf(r1); r2 = leakyf(r2); r3 = leakyf(r3); }
    float4 rv = make_float4(r0, r1, r2, r3);
    *(float4*)(jb.D + (size_t)gr * 128 + c0) = rv;
  }
}

// ---------------- classifier head: U = x_drug@cw0_top + b0, V = x_dis@cw0_bot ----------------
struct G64Job { const float* X; const float* W; const float* bias; float* D; int M; };

__global__ __launch_bounds__(256) void k_gemm64(G64Job j0, G64Job j1) {
  G64Job jb = blockIdx.z ? j1 : j0;
  int m0 = blockIdx.x * 64;
  if (m0 >= jb.M) return;
  __shared__ float As[16][68];
  __shared__ float Bs[16][68];
  int tid = threadIdx.x;
  int tx = tid & 15, ty = tid >> 4;   // cols tx*4..+3, rows ty*4..+3
  float acc[4][4];
  #pragma unroll
  for (int i = 0; i < 4; i++)
    #pragma unroll
    for (int j = 0; j < 4; j++) acc[i][j] = 0.f;

  for (int kk = 0; kk < 128; kk += 16) {
    {
      int r = tid >> 2, kq = (tid & 3) * 4;
      int gr = m0 + r;
      float4 v = make_float4(0.f, 0.f, 0.f, 0.f);
      if (gr < jb.M) v = *(const float4*)(jb.X + (size_t)gr * HC + kk + kq);
      As[kq + 0][r] = v.x; As[kq + 1][r] = v.y; As[kq + 2][r] = v.z; As[kq + 3][r] = v.w;
    }
    {
      int k = tid >> 4, c = (tid & 15) * 4;
      *(float4*)&Bs[k][c] = *(const float4*)(jb.W + (size_t)(kk + k) * 64 + c);
    }
    __syncthreads();
    #pragma unroll
    for (int k = 0; k < 16; k++) {
      float4 a = *(const float4*)&As[k][ty * 4];
      float4 b = *(const float4*)&Bs[k][tx * 4];
      float av[4] = {a.x, a.y, a.z, a.w};
      float bb[4] = {b.x, b.y, b.z, b.w};
      #pragma unroll
      for (int i = 0; i < 4; i++)
        #pragma unroll
        for (int j = 0; j < 4; j++) acc[i][j] += av[i] * bb[j];
    }
    __syncthreads();
  }
  float4 bs = make_float4(0.f, 0.f, 0.f, 0.f);
  if (jb.bias) bs = *(const float4*)(jb.bias + tx * 4);
  #pragma unroll
  for (int i = 0; i < 4; i++) {
    int gr = m0 + ty * 4 + i;
    if (gr < jb.M) {
      float4 r = make_float4(acc[i][0] + bs.x, acc[i][1] + bs.y, acc[i][2] + bs.z, acc[i][3] + bs.w);
      *(float4*)(jb.D + (size_t)gr * 64 + tx * 4) = r;
    }
  }
}

// ---------------- per-edge tail MLP: h1=leaky(U[s]+V[d]); 64->32->16->8->1 ----------------
__global__ __launch_bounds__(256) void k_tail(
    const float* __restrict__ U, const float* __restrict__ V,
    const int* __restrict__ es, const int* __restrict__ ed,
    const float* __restrict__ cw1, const float* __restrict__ cb1,
    const float* __restrict__ cw2, const float* __restrict__ cb2,
    const float* __restrict__ cw3, const float* __restrict__ cb3,
    const float* __restrict__ cw4, const float* __restrict__ cb4,
    float* __restrict__ out, int n) {
  int i = blockIdx.x * blockDim.x + threadIdx.x;
  if (i >= n) return;
  int s = es[i], d = ed[i];
  const float4* up = (const float4*)(U + (size_t)s * 64);
  const float4* vp = (const float4*)(V + (size_t)d * 64);
  float h1[64];
  #pragma unroll
  for (int q = 0; q < 16; q++) {
    float4 a = up[q], b = vp[q];
    h1[4 * q + 0] = leakyf(a.x + b.x);
    h1[4 * q + 1] = leakyf(a.y + b.y);
    h1[4 * q + 2] = leakyf(a.z + b.z);
    h1[4 * q + 3] = leakyf(a.w + b.w);
  }
  float h2[32];
  #pragma unroll
  for (int j = 0; j < 32; j++) h2[j] = cb1[j];
  #pragma unroll 4
  for (int k = 0; k < 64; k++) {
    float hv = h1[k];
    #pragma unroll
    for (int j = 0; j < 32; j++) h2[j] = fmaf(hv, cw1[k * 32 + j], h2[j]);
  }
  #pragma unroll
  for (int j = 0; j < 32; j++) h2[j] = leakyf(h2[j]);
  float h3[16];
  #pragma unroll
  for (int j = 0; j < 16; j++) h3[j] = cb2[j];
  #pragma unroll 8
  for (int k = 0; k < 32; k++) {
    float hv = h2[k];
    #pragma unroll
    for (int j = 0; j < 16; j++) h3[j] = fmaf(hv, cw2[k * 16 + j], h3[j]);
  }
  #pragma unroll
  for (int j = 0; j < 16; j++) h3[j] = leakyf(h3[j]);
  float h4[8];
  #pragma unroll
  for (int j = 0; j < 8; j++) h4[j] = cb3[j];
  #pragma unroll
  for (int k = 0; k < 16; k++) {
    float hv = h3[k];
    #pragma unroll
    for (int j = 0; j < 8; j++) h4[j] = fmaf(hv, cw3[k * 8 + j], h4[j]);
  }
  float p = cb4[0];
  #pragma unroll
  for (int k = 0; k < 8; k++) p = fmaf(leakyf(h4[k]), cw4[k], p);
  out[i] = p;
}

extern "C" void kernel_launch(void* const* d_in, const int* in_sizes, int n_in,
                              void* d_out, int out_size, void* d_ws, size_t ws_size,
                              hipStream_t stream) {
  const float* disease_x   = (const float*)d_in[0];
  const float* drug_emb    = (const float*)d_in[1];
  const float* disease_emb = (const float*)d_in[2];
  const float* attr_emb    = (const float*)d_in[3];
  const float* dis_lin_w   = (const float*)d_in[4];
  const float* dis_lin_b   = (const float*)d_in[5];
  const float* mt_wl  = (const float*)d_in[6];
  const float* mt_bl  = (const float*)d_in[7];
  const float* mt_wr  = (const float*)d_in[8];
  const float* rmt_wl = (const float*)d_in[9];
  const float* rmt_bl = (const float*)d_in[10];
  const float* rmt_wr = (const float*)d_in[11];
  const float* ha_wl  = (const float*)d_in[12];
  const float* ha_bl  = (const float*)d_in[13];
  const float* ha_wr  = (const float*)d_in[14];
  const float* rha_wl = (const float*)d_in[15];
  const float* rha_bl = (const float*)d_in[16];
  const float* rha_wr = (const float*)d_in[17];
  const float* cw0 = (const float*)d_in[18];
  const float* cb0 = (const float*)d_in[19];
  const float* cw1 = (const float*)d_in[20];
  const float* cb1 = (const float*)d_in[21];
  const float* cw2 = (const float*)d_in[22];
  const float* cb2 = (const float*)d_in[23];
  const float* cw3 = (const float*)d_in[24];
  const float* cb3 = (const float*)d_in[25];
  const float* cw4 = (const float*)d_in[26];
  const float* cb4 = (const float*)d_in[27];
  const int* mt_src = (const int*)d_in[28];
  const int* mt_dst = (const int*)d_in[29];
  const int* ha_src = (const int*)d_in[30];
  const int* ha_dst = (const int*)d_in[31];
  const int* ell_src = (const int*)d_in[32];
  const int* ell_dst = (const int*)d_in[33];
  float* out = (float*)d_out;

  const long long ATTR_S = (long long)N_ATTR * HC;
  const long long W_S = HC * HC;

  // ---------- workspace carve ----------
  float* fws = (float*)d_ws;
  size_t o = 0;
  float* x_drug = fws + o; o += (size_t)N_DRUG * HC;
  float* x_dis  = fws + o; o += (size_t)N_DIS * HC;
  float* x_attr = fws + o; o += (size_t)T_ATTR * N_ATTR * HC;
  float* Ydis   = fws + o; o += (size_t)N_DIS * HC;
  float* Yattr  = fws + o; o += (size_t)T_ATTR * N_ATTR * HC;
  float* m2dis  = fws + o; o += (size_t)N_DIS * HC;
  float* m2a    = fws + o; o += (size_t)T_ATTR * N_ATTR * HC;
  float* accd   = fws + o; o += (size_t)N_DRUG * HC;
  float* Wc     = fws + o; o += HC * HC;
  float* biasc  = fws + o; o += HC;
  float* Ucls   = fws + o; o += (size_t)N_DRUG * 64;
  float* Vcls   = fws + o; o += (size_t)N_DIS * 64;
  int* iws = (int*)(fws + o);
  int* cnt = iws;
  int* off = cnt + 206000;
  int* cur = off + 206018;
  int* val_mt_dst = cur + 206000;
  int* val_mt_src = val_mt_dst + E_MT;
  int* val_ha_dst = val_mt_src + E_MT;
  int* val_ha_src = val_ha_dst + (size_t)T_ATTR * E_HA;

  dim3 b256(256);
  // ---------- CSR build ----------
  hipMemsetAsync(cnt, 0, 206000 * sizeof(int), stream);
  k_count_all<<<dim3(512, 1, 18), b256, 0, stream>>>(mt_src, mt_dst, ha_src, ha_dst, cnt);
  k_scan<<<18, 256, 0, stream>>>(cnt, off, cur);
  k_fill_all<<<dim3(512, 1, 18), b256, 0, stream>>>(mt_src, mt_dst, ha_src, ha_dst, cur,
                                                    val_mt_dst, val_mt_src, val_ha_dst, val_ha_src);

  // ---------- node init ----------
  k_dis0<<<N_DIS, 128, 0, stream>>>(disease_x, dis_lin_w, dis_lin_b, disease_emb, x_dis);

  for (int l = 0; l < 2; l++) {
    const float* xd = l ? (const float*)x_drug : drug_emb;
    const float* xa = l ? (const float*)x_attr : attr_emb;
    const float* mt_wl_l  = mt_wl  + (size_t)l * W_S;
    const float* mt_bl_l  = mt_bl  + (size_t)l * HC;
    const float* mt_wr_l  = mt_wr  + (size_t)l * W_S;
    const float* rmt_wl_l = rmt_wl + (size_t)l * W_S;
    const float* ha_wl_l  = ha_wl  + (size_t)l * T_ATTR * W_S;
    const float* ha_bl_l  = ha_bl  + (size_t)l * T_ATTR * HC;
    const float* ha_wr_l  = ha_wr  + (size_t)l * T_ATTR * W_S;
    const float* rha_wl_l = rha_wl + (size_t)l * T_ATTR * W_S;

    k_wc<<<64, 256, 0, stream>>>(rmt_wr + (size_t)l * W_S, rha_wr + (size_t)l * T_ATTR * W_S,
                                 rmt_bl + (size_t)l * HC, rha_bl + (size_t)l * T_ATTR * HC, Wc, biasc);

    // pre-transform GEMMs on the small side: Ydis = x_dis@rmt_wl, Yattr_t = x_attr_t@rha_wl_t
    {
      GemmJobs J{};
      J.j[0] = {x_dis, rmt_wl_l, nullptr, nullptr, nullptr, nullptr, Ydis, N_DIS, 0};
      for (int t = 0; t < T_ATTR; t++)
        J.j[1 + t] = {xa + (size_t)t * ATTR_S, rha_wl_l + (size_t)t * W_S,
                      nullptr, nullptr, nullptr, nullptr, Yattr + (size_t)t * ATTR_S, N_ATTR, 0};
      k_gemm_multi<<<dim3((N_DIS + 63) / 64, 1, 9), b256, 0, stream>>>(J);
    }

    // all gathers of this layer
    k_seg_mega<<<dim3((46000 + 3) / 4, 1, 1), b256, 0, stream>>>(
        off, val_mt_dst, val_mt_src, val_ha_dst, val_ha_src,
        xd, Ydis, Yattr, m2dis, accd, m2a);

    // combine GEMMs (fused bias + leaky, in-place row-aligned writes)
    {
      GemmJobs J{};
      J.j[0] = {xd, Wc, nullptr, nullptr, biasc, accd, x_drug, N_DRUG, 1};
      J.j[1] = {m2dis, mt_wl_l, x_dis, mt_wr_l, mt_bl_l, nullptr, x_dis, N_DIS, 1};
      for (int t = 0; t < T_ATTR; t++)
        J.j[2 + t] = {m2a + (size_t)t * ATTR_S, ha_wl_l + (size_t)t * W_S,
                      xa + (size_t)t * ATTR_S, ha_wr_l + (size_t)t * W_S,
                      ha_bl_l + (size_t)t * HC, nullptr, x_attr + (size_t)t * ATTR_S, N_ATTR, 1};
      k_gemm_multi<<<dim3((N_DRUG + 63) / 64, 1, 10), b256, 0, stream>>>(J);
    }
  }

  // ---------- classifier: U/V precompute then per-edge tail ----------
  {
    G64Job ju = {x_drug, cw0, cb0, Ucls, N_DRUG};
    G64Job jv = {x_dis, cw0 + 128 * 64, nullptr, Vcls, N_DIS};
    k_gemm64<<<dim3((N_DRUG + 63) / 64, 1, 2), b256, 0, stream>>>(ju, jv);
    k_tail<<<dim3((E_LBL + 255) / 256, 1, 1), b256, 0, stream>>>(
        Ucls, Vcls, ell_src, ell_dst,
        cw1, cb1, cw2, cb2, cw3, cb3, cw4, cb4, out, E_LBL);
  }
}